// Round 2
// baseline (185.237 us; speedup 1.0000x reference)
//
#include <hip/hip_runtime.h>

#define HH 260
#define WW 346
#define CC 1212            // 2H + 2W
#define BB 16
#define TT 4096
#define INV_TEMP (1.0f/256.0f)
#define KCH 256            // chunks per batch
#define LCH (TT / KCH)     // 16 steps per chunk
#define NJ 19              // ceil(CC/64) channels per lane

// ---------------- Phase 1: per-chunk local state (zero carry), 1 wave/block ----------------
__global__ __launch_bounds__(64) void p1_local(const float* __restrict__ target,
                                               float* __restrict__ Lbuf) {
    const int blk = blockIdx.x;
    const int b = blk >> 8, k = blk & (KCH - 1);
    const int a = k * LCH;
    const int lane = threadIdx.x;

    __shared__ float tg[LCH][4];   // LCH*4 == 64
    __shared__ float tnextS;
    tg[lane >> 2][lane & 3] = target[((size_t)b * TT + a) * 4 + lane];
    if (lane == 0) tnextS = (a + LCH < TT) ? target[((size_t)b * TT + a + LCH) * 4] : 0.0f;
    __syncthreads();

    float s[NJ];
#pragma unroll
    for (int j = 0; j < NJ; ++j) s[j] = 0.0f;

    for (int li = LCH - 1; li >= 0; --li) {
        const int i = a + li;
        const float ti = tg[li][0];
        const float tn = (li == LCH - 1) ? tnextS : tg[li + 1][0];
        const float d = (i >= TT - 1) ? 0.0f : __expf(-(tn - ti) * INV_TEMP);
        const int y = (int)tg[li][1], x = (int)tg[li][2], p = (int)tg[li][3];
        const int yc = p * HH + y;
        const int xc = 2 * HH + p * WW + x;
#pragma unroll
        for (int j = 0; j < NJ; ++j) {
            const int c = lane + j * 64;
            const float add = (c == yc ? 1.0f : 0.0f) + (c == xc ? 1.0f : 0.0f);
            s[j] = fmaf(s[j], d, add);
        }
    }

    const size_t base = (size_t)blk * CC;
#pragma unroll
    for (int j = 0; j < NJ; ++j) {
        const int c = lane + j * 64;
        if (c < CC) Lbuf[base + c] = s[j];
    }
}

// ------- Phase 2: sequential chunk combine -> carry_in per chunk (out of place) -------
__global__ void p2_carry(const float* __restrict__ target,
                         const float* __restrict__ Lbuf,
                         float* __restrict__ Cbuf) {
    const int gid = blockIdx.x * blockDim.x + threadIdx.x;
    if (gid >= BB * CC) return;
    const int b = gid / CC, c = gid - b * CC;
    float carry = 0.0f;   // carry_in(K-1) = 0
#pragma unroll 4
    for (int k = KCH - 1; k >= 0; --k) {
        const size_t idx = ((size_t)(b * KCH + k)) * CC + c;
        Cbuf[idx] = carry;               // carry_in(k)
        float P = 0.0f;
        if (k < KCH - 1) {
            const float ta = target[((size_t)b * TT + k * LCH) * 4];
            const float te = target[((size_t)b * TT + k * LCH + LCH) * 4];
            P = __expf(-(te - ta) * INV_TEMP);
        }
        carry = fmaf(P, carry, Lbuf[idx]);   // S_k = L_k + P_k * carry_in(k)
    }
}

// ---------------- Phase 3: replay with true carry + fused loss, 1 wave/block ----------------
__global__ __launch_bounds__(64) void p3_loss(const float* __restrict__ pred,
                                              const float* __restrict__ target,
                                              const float* __restrict__ Cbuf,
                                              double* __restrict__ partials) {
    const int blk = blockIdx.x;
    const int b = blk >> 8, k = blk & (KCH - 1);
    const int a = k * LCH;
    const int lane = threadIdx.x;

    __shared__ float tg[LCH][4];
    __shared__ float tnextS;
    tg[lane >> 2][lane & 3] = target[((size_t)b * TT + a) * 4 + lane];
    if (lane == 0) tnextS = (a + LCH < TT) ? target[((size_t)b * TT + a + LCH) * 4] : 0.0f;
    __syncthreads();

    float s[NJ];
    const size_t cbase = (size_t)blk * CC;
#pragma unroll
    for (int j = 0; j < NJ; ++j) {
        const int c = lane + j * 64;
        s[j] = (c < CC) ? Cbuf[cbase + c] : 0.0f;
    }

    float prA[NJ], prB[NJ];
    // prefetch row li = LCH-1 (active channels only)
    {
        const int p = (int)tg[LCH - 1][3];
        const int y0 = p * HH, x0 = 2 * HH + p * WW;
        const float* __restrict__ prow = pred + ((size_t)b * TT + a + LCH - 1) * CC;
#pragma unroll
        for (int j = 0; j < NJ; ++j) {
            const int c = lane + j * 64;
            if ((unsigned)(c - y0) < (unsigned)HH || (unsigned)(c - x0) < (unsigned)WW)
                prA[j] = prow[c];
            else
                prA[j] = 0.0f;
        }
    }

    double lacc = 0.0;
    for (int li = LCH - 1; li >= 0; --li) {
        // issue next row's loads before the compute of this row
        if (li > 0) {
            const int p = (int)tg[li - 1][3];
            const int y0 = p * HH, x0 = 2 * HH + p * WW;
            const float* __restrict__ prow = pred + ((size_t)b * TT + a + li - 1) * CC;
#pragma unroll
            for (int j = 0; j < NJ; ++j) {
                const int c = lane + j * 64;
                if ((unsigned)(c - y0) < (unsigned)HH || (unsigned)(c - x0) < (unsigned)WW)
                    prB[j] = prow[c];
                else
                    prB[j] = 0.0f;
            }
        }

        const int i = a + li;
        const float ti = tg[li][0];
        const float tn = (li == LCH - 1) ? tnextS : tg[li + 1][0];
        const float d = (i == 0 || i >= TT - 1) ? 0.0f : __expf(-(tn - ti) * INV_TEMP);
        const int y = (int)tg[li][1], x = (int)tg[li][2], p = (int)tg[li][3];
        const int yc = p * HH + y;
        const int xc = 2 * HH + p * WW + x;
        const int y0 = p * HH, x0 = 2 * HH + p * WW;

        float zp_y = 0.f, zs_y = 0.f, dt_y = 0.f;
        float zp_x = 0.f, zs_x = 0.f, dt_x = 0.f;
#pragma unroll
        for (int j = 0; j < NJ; ++j) {
            const int c = lane + j * 64;
            const float add = (c == yc ? 1.0f : 0.0f) + (c == xc ? 1.0f : 0.0f);
            s[j] = fmaf(s[j], d, add);
            const unsigned dy = (unsigned)(c - y0);
            const unsigned dx = (unsigned)(c - x0);
            if (dy < (unsigned)HH) {
                const float pr = prA[j];
                const float es = __expf(s[j]);
                zp_y += __expf(pr);
                zs_y += es;
                dt_y = fmaf(es, pr, dt_y);
            } else if (dx < (unsigned)WW) {
                const float pr = prA[j];
                const float es = __expf(s[j]);
                zp_x += __expf(pr);
                zs_x += es;
                dt_x = fmaf(es, pr, dt_x);
            }
        }
        // 64-lane butterfly: afterwards ALL lanes hold the totals
#pragma unroll
        for (int off = 32; off > 0; off >>= 1) {
            zp_y += __shfl_xor(zp_y, off);
            zs_y += __shfl_xor(zs_y, off);
            dt_y += __shfl_xor(dt_y, off);
            zp_x += __shfl_xor(zp_x, off);
            zs_x += __shfl_xor(zs_x, off);
            dt_x += __shfl_xor(dt_x, off);
        }
        // redundant in every lane -> no serialization, no barrier
        const float loss = __logf(zp_y) + __logf(zp_x)
                         - __fdividef(dt_y, zs_y) - __fdividef(dt_x, zs_x);
        lacc += (double)loss;

#pragma unroll
        for (int j = 0; j < NJ; ++j) prA[j] = prB[j];
    }
    if (lane == 0) partials[blk] = lacc;
}

// ---------------- Finalize: deterministic reduction of block partials ----------------
__global__ void p4_final(const double* __restrict__ partials, float* __restrict__ out) {
    const int tid = threadIdx.x;   // 256
    double sum = 0.0;
    for (int i = tid; i < BB * KCH; i += 256) sum += partials[i];
#pragma unroll
    for (int off = 32; off > 0; off >>= 1) sum += __shfl_xor(sum, off);
    __shared__ double sred[4];
    if ((tid & 63) == 0) sred[tid >> 6] = sum;
    __syncthreads();
    if (tid == 0)
        out[0] = (float)((sred[0] + sred[1] + sred[2] + sred[3]) / (double)((size_t)BB * TT));
}

extern "C" void kernel_launch(void* const* d_in, const int* in_sizes, int n_in,
                              void* d_out, int out_size, void* d_ws, size_t ws_size,
                              hipStream_t stream) {
    const float* pred   = (const float*)d_in[0];
    const float* target = (const float*)d_in[1];
    float* out = (float*)d_out;

    // ws layout: [ partials: BB*KCH doubles (<=32KB, pad to 64KB) ][ Lbuf ][ Cbuf ]
    double* partials = (double*)d_ws;
    float* Lbuf = (float*)((char*)d_ws + 65536);
    float* Cbuf = Lbuf + (size_t)BB * KCH * CC;

    p1_local<<<BB * KCH, 64, 0, stream>>>(target, Lbuf);
    p2_carry<<<(BB * CC + 255) / 256, 256, 0, stream>>>(target, Lbuf, Cbuf);
    p3_loss<<<BB * KCH, 64, 0, stream>>>(pred, target, Cbuf, partials);
    p4_final<<<1, 256, 0, stream>>>(partials, out);
}

// Round 3
// 84.387 us; speedup vs baseline: 2.1951x; 2.1951x over previous
//
#include <hip/hip_runtime.h>

#define HH 260
#define WW 346
#define CC 1212            // real channel count (pred layout)
#define CP 1280            // padded compact space: [0,640) pol0, [640,1280) pol1
#define HALF 640
#define NA 606             // active channels per polarity (260 + 346)
#define BB 16
#define TT 4096
#define INV_TEMP (1.0f/256.0f)
#define KCH 256            // chunks per batch
#define LCH 16             // TT / KCH
#define NG 16              // groups per batch
#define GSZ 16             // chunks per group
#define NJ 10              // compact registers per polarity set (640/64)

// ---------------- Phase 1: per-chunk local state (zero carry), compact layout ----------------
__global__ __launch_bounds__(64) void p1_local(const float* __restrict__ target,
                                               float* __restrict__ Lbuf) {
    const int blk = blockIdx.x;
    const int b = blk >> 8, k = blk & (KCH - 1);
    const int a = k * LCH;
    const int lane = threadIdx.x;

    __shared__ float tg[LCH][4];
    __shared__ float tnextS;
    tg[lane >> 2][lane & 3] = target[((size_t)b * TT + a) * 4 + lane];
    if (lane == 0) tnextS = (a + LCH < TT) ? target[((size_t)b * TT + a + LCH) * 4] : 0.0f;
    __syncthreads();

    float s0[NJ], s1[NJ];
#pragma unroll
    for (int j = 0; j < NJ; ++j) { s0[j] = 0.f; s1[j] = 0.f; }

    for (int li = LCH - 1; li >= 0; --li) {
        const int i = a + li;
        const float ti = tg[li][0];
        const float tn = (li == LCH - 1) ? tnextS : tg[li + 1][0];
        const float d = (i >= TT - 1) ? 0.0f : __expf(-(tn - ti) * INV_TEMP);
        const int y = (int)tg[li][1], x = (int)tg[li][2], p = (int)tg[li][3];
        const int uy = y, ux = 260 + x;
        if (p == 0) {
#pragma unroll
            for (int j = 0; j < NJ; ++j) {
                const int u = lane + 64 * j;
                const float add = (u == uy ? 1.f : 0.f) + (u == ux ? 1.f : 0.f);
                s0[j] = fmaf(s0[j], d, add);
                s1[j] *= d;
            }
        } else {
#pragma unroll
            for (int j = 0; j < NJ; ++j) {
                const int u = lane + 64 * j;
                const float add = (u == uy ? 1.f : 0.f) + (u == ux ? 1.f : 0.f);
                s1[j] = fmaf(s1[j], d, add);
                s0[j] *= d;
            }
        }
    }
    float* __restrict__ out = Lbuf + (size_t)blk * CP;
#pragma unroll
    for (int j = 0; j < NJ; ++j) {
        out[lane + 64 * j] = s0[j];
        out[HALF + lane + 64 * j] = s1[j];
    }
}

// ------- Phase 2a: within-group (16 chunks) suffix combine -------
__global__ __launch_bounds__(256) void p2a(const float* __restrict__ target,
                                           const float* __restrict__ Lbuf,
                                           float* __restrict__ LCin,
                                           float* __restrict__ GroupL) {
    const int blk = blockIdx.x;            // BB*NG*5
    const int ct = blk % 5;
    const int bg = blk / 5;                // b*NG + g
    const int b = bg >> 4, g = bg & 15;
    const int c = ct * 256 + threadIdx.x;  // < CP

    float carry = 0.f;
#pragma unroll
    for (int kk = GSZ - 1; kk >= 0; --kk) {
        const int k = g * GSZ + kk;
        const size_t idx = ((size_t)(b * KCH + k)) * CP + c;
        LCin[idx] = carry;
        float P = 0.f;
        if (k < KCH - 1) {
            const float ta = target[((size_t)b * TT + k * LCH) * 4];
            const float te = target[((size_t)b * TT + (k + 1) * LCH) * 4];
            P = __expf(-(te - ta) * INV_TEMP);
        }
        carry = fmaf(P, carry, Lbuf[idx]);
    }
    GroupL[(size_t)bg * CP + c] = carry;
}

// ------- Phase 2b: super-scan across 16 groups -------
__global__ __launch_bounds__(256) void p2b(const float* __restrict__ target,
                                           const float* __restrict__ GroupL,
                                           float* __restrict__ SC) {
    const int blk = blockIdx.x;            // BB*5
    const int ct = blk % 5;
    const int b = blk / 5;
    const int c = ct * 256 + threadIdx.x;

    float carry = 0.f;
#pragma unroll
    for (int g = NG - 1; g >= 0; --g) {
        const size_t idx = ((size_t)(b * NG + g)) * CP + c;
        SC[idx] = carry;
        float GP = 0.f;
        if (g < NG - 1) {
            const float ta = target[((size_t)b * TT + g * (GSZ * LCH)) * 4];
            const float te = target[((size_t)b * TT + (g + 1) * (GSZ * LCH)) * 4];
            GP = __expf(-(te - ta) * INV_TEMP);
        }
        carry = fmaf(GP, carry, GroupL[idx]);
    }
}

// ---------------- Phase 3: replay with true carry + fused loss ----------------
__global__ __launch_bounds__(64) void p3_loss(const float* __restrict__ pred,
                                              const float* __restrict__ target,
                                              const float* __restrict__ LCin,
                                              const float* __restrict__ SC,
                                              double* __restrict__ partials) {
    const int blk = blockIdx.x;
    const int b = blk >> 8, k = blk & (KCH - 1);
    const int g = k >> 4;
    const int a = k * LCH;
    const int lane = threadIdx.x;

    __shared__ float tg[LCH][4];
    __shared__ float tnextS;
    tg[lane >> 2][lane & 3] = target[((size_t)b * TT + a) * 4 + lane];
    if (lane == 0) tnextS = (a + LCH < TT) ? target[((size_t)b * TT + a + LCH) * 4] : 0.0f;
    __syncthreads();

    // carry(k) = LCin[k] + Qk * SC[group], Qk = exp(-(t[groupEnd] - t[a_{k+1}])/T)
    float Qk = 0.f;
    if (g < NG - 1) {
        const float tge = target[((size_t)b * TT + (g + 1) * (GSZ * LCH)) * 4];
        const float tk1 = target[((size_t)b * TT + (k + 1) * LCH) * 4];
        Qk = __expf(-(tge - tk1) * INV_TEMP);
    }

    const float* __restrict__ lc = LCin + (size_t)blk * CP;
    const float* __restrict__ sc = SC + ((size_t)(b * NG + g)) * CP;
    float s0[NJ], s1[NJ];
#pragma unroll
    for (int j = 0; j < NJ; ++j) {
        const int u = lane + 64 * j;
        s0[j] = fmaf(Qk, sc[u], lc[u]);
        s1[j] = fmaf(Qk, sc[HALF + u], lc[HALF + u]);
    }

    float prA[NJ], prB[NJ];
    {
        const int p = (int)tg[LCH - 1][3];
        const float* __restrict__ prow = pred + ((size_t)b * TT + a + LCH - 1) * CC;
#pragma unroll
        for (int j = 0; j < NJ; ++j) {
            const int u = lane + 64 * j;
            const int c = (u < 260) ? p * HH + u : 2 * HH + p * WW + (u - 260);
            prA[j] = (u < NA) ? prow[c] : 0.0f;
        }
    }

    double lacc = 0.0;
    for (int li = LCH - 1; li >= 0; --li) {
        if (li > 0) {
            const int pn = (int)tg[li - 1][3];
            const float* __restrict__ prow = pred + ((size_t)b * TT + a + li - 1) * CC;
#pragma unroll
            for (int j = 0; j < NJ; ++j) {
                const int u = lane + 64 * j;
                const int c = (u < 260) ? pn * HH + u : 2 * HH + pn * WW + (u - 260);
                prB[j] = (u < NA) ? prow[c] : 0.0f;
            }
        }

        const int i = a + li;
        const float ti = tg[li][0];
        const float tn = (li == LCH - 1) ? tnextS : tg[li + 1][0];
        const float d = (i == 0 || i >= TT - 1) ? 0.0f : __expf(-(tn - ti) * INV_TEMP);
        const int y = (int)tg[li][1], x = (int)tg[li][2], p = (int)tg[li][3];
        const int uy = y, ux = 260 + x;

        float zpy = 0.f, zsy = 0.f, dty = 0.f;
        float zpx = 0.f, zsx = 0.f, dtx = 0.f;

        auto stepActive = [&](float (&SA)[NJ], float (&SO)[NJ]) {
#pragma unroll
            for (int j = 0; j < NJ; ++j) {
                const int u = lane + 64 * j;
                const float add = (u == uy ? 1.f : 0.f) + (u == ux ? 1.f : 0.f);
                SA[j] = fmaf(SA[j], d, add);
                SO[j] *= d;
                float es = __expf(SA[j]);
                float ep = __expf(prA[j]);
                if (j == NJ - 1) {               // mask pad lanes (u >= 606)
                    const float m = (u < NA) ? 1.f : 0.f;
                    es *= m; ep *= m;
                }
                if (j < 4) {                     // u <= 255: pure y
                    zpy += ep; zsy += es; dty = fmaf(es, prA[j], dty);
                } else if (j == 4) {             // u in [256,320): mixed at 260
                    const bool isY = (u < 260);
                    zpy += isY ? ep : 0.f;
                    zsy += isY ? es : 0.f;
                    dty = fmaf(isY ? es : 0.f, prA[j], dty);
                    zpx += isY ? 0.f : ep;
                    zsx += isY ? 0.f : es;
                    dtx = fmaf(isY ? 0.f : es, prA[j], dtx);
                } else {                         // pure x
                    zpx += ep; zsx += es; dtx = fmaf(es, prA[j], dtx);
                }
            }
        };
        if (p == 0) stepActive(s0, s1); else stepActive(s1, s0);

#pragma unroll
        for (int off = 32; off > 0; off >>= 1) {
            zpy += __shfl_xor(zpy, off);
            zsy += __shfl_xor(zsy, off);
            dty += __shfl_xor(dty, off);
            zpx += __shfl_xor(zpx, off);
            zsx += __shfl_xor(zsx, off);
            dtx += __shfl_xor(dtx, off);
        }
        const float loss = __logf(zpy) + __logf(zpx)
                         - __fdividef(dty, zsy) - __fdividef(dtx, zsx);
        lacc += (double)loss;

#pragma unroll
        for (int j = 0; j < NJ; ++j) prA[j] = prB[j];
    }
    if (lane == 0) partials[blk] = lacc;
}

// ---------------- Finalize ----------------
__global__ void p4_final(const double* __restrict__ partials, float* __restrict__ out) {
    const int tid = threadIdx.x;   // 256
    double sum = 0.0;
    for (int i = tid; i < BB * KCH; i += 256) sum += partials[i];
#pragma unroll
    for (int off = 32; off > 0; off >>= 1) sum += __shfl_xor(sum, off);
    __shared__ double sred[4];
    if ((tid & 63) == 0) sred[tid >> 6] = sum;
    __syncthreads();
    if (tid == 0)
        out[0] = (float)((sred[0] + sred[1] + sred[2] + sred[3]) / (double)((size_t)BB * TT));
}

extern "C" void kernel_launch(void* const* d_in, const int* in_sizes, int n_in,
                              void* d_out, int out_size, void* d_ws, size_t ws_size,
                              hipStream_t stream) {
    const float* pred   = (const float*)d_in[0];
    const float* target = (const float*)d_in[1];
    float* out = (float*)d_out;

    // ws layout: [partials 4096 doubles (pad 64KB)][Lbuf][LCin][GroupL][SC]
    double* partials = (double*)d_ws;
    float* Lbuf   = (float*)((char*)d_ws + 65536);
    float* LCin   = Lbuf + (size_t)BB * KCH * CP;
    float* GroupL = LCin + (size_t)BB * KCH * CP;
    float* SC     = GroupL + (size_t)BB * NG * CP;

    p1_local<<<BB * KCH, 64, 0, stream>>>(target, Lbuf);
    p2a<<<BB * NG * 5, 256, 0, stream>>>(target, Lbuf, LCin, GroupL);
    p2b<<<BB * 5, 256, 0, stream>>>(target, GroupL, SC);
    p3_loss<<<BB * KCH, 64, 0, stream>>>(pred, target, LCin, SC, partials);
    p4_final<<<1, 256, 0, stream>>>(partials, out);
}